// Round 16
// baseline (66.970 us; speedup 1.0000x reference)
//
#include <hip/hip_runtime.h>
#include <hip/hip_bf16.h>

// MoE forward, top-2 sparse gather-GEMM.
// T=2048, D=512, F=1024, E=8, top-2. fp32 in/out, bf16 MFMA internally.
//
// Round 16 = R15 (66.7us) + ONE parameter change: gemm2 split-K 2 -> 4.
//   gemm2: 1280 blocks (5/CU vs 2.5/CU) -> better latency hiding; K=256/block,
//   8 K-steps; outp = [4][PCAP][D] bf16; gather sums 8 partials.
//   Everything else byte-identical to R15.

typedef __attribute__((ext_vector_type(4))) float f32x4;
typedef __attribute__((ext_vector_type(8))) __bf16 bf16x8;

#define T_TOK 2048
#define DMODEL 512
#define FFN 1024
#define NE 8
#define MAXMB 40
#define PCAP (MAXMB * 128)

__device__ __forceinline__ void gload_lds16(const void* g, void* l) {
  __builtin_amdgcn_global_load_lds(
      (const __attribute__((address_space(1))) void*)g,
      (__attribute__((address_space(3))) void*)l, 16, 0, 0);
}

#define PIPE_BAR_4()                                        \
  asm volatile("s_waitcnt vmcnt(4)" ::: "memory");          \
  __builtin_amdgcn_s_barrier();                             \
  __builtin_amdgcn_sched_barrier(0)
#define PIPE_BAR_3()                                        \
  asm volatile("s_waitcnt vmcnt(3)" ::: "memory");          \
  __builtin_amdgcn_s_barrier();                             \
  __builtin_amdgcn_sched_barrier(0)
#define PIPE_BAR_0()                                        \
  asm volatile("s_waitcnt vmcnt(0)" ::: "memory");          \
  __builtin_amdgcn_s_barrier();                             \
  __builtin_amdgcn_sched_barrier(0)
#define POST_BAR()                                          \
  __builtin_amdgcn_s_barrier();                             \
  __builtin_amdgcn_sched_barrier(0)

// ---------------- k1: router (x->bf16 + top-2) + inits ----------------
__global__ __launch_bounds__(256) void router_kernel(
    const float* __restrict__ x, const float* __restrict__ rw,
    __bf16* __restrict__ xb, int* __restrict__ tope, float* __restrict__ topw,
    int* __restrict__ pair_t, float* __restrict__ pair_w,
    int* __restrict__ sched_e) {
  const int bx = blockIdx.x;
  const int tid = threadIdx.x;
  if (bx < 512) {
    const int t = bx * 4 + (tid >> 6);
    const int lane = tid & 63;
    const float* xr = x + (size_t)t * DMODEL + lane * 8;
    const f32x4 a = *(const f32x4*)xr;
    const f32x4 b = *(const f32x4*)(xr + 4);
    bf16x8 v;
    v[0] = (__bf16)a[0]; v[1] = (__bf16)a[1]; v[2] = (__bf16)a[2]; v[3] = (__bf16)a[3];
    v[4] = (__bf16)b[0]; v[5] = (__bf16)b[1]; v[6] = (__bf16)b[2]; v[7] = (__bf16)b[3];
    *(bf16x8*)&xb[(size_t)t * DMODEL + lane * 8] = v;

    float xv[8] = {a[0], a[1], a[2], a[3], b[0], b[1], b[2], b[3]};
    float part[NE];
#pragma unroll
    for (int e = 0; e < NE; ++e) part[e] = 0.f;
#pragma unroll
    for (int i = 0; i < 8; ++i) {
      const int d = lane * 8 + i;
      const f32x4 r0 = *(const f32x4*)&rw[(size_t)d * NE];
      const f32x4 r1 = *(const f32x4*)&rw[(size_t)d * NE + 4];
      part[0] += xv[i] * r0[0]; part[1] += xv[i] * r0[1];
      part[2] += xv[i] * r0[2]; part[3] += xv[i] * r0[3];
      part[4] += xv[i] * r1[0]; part[5] += xv[i] * r1[1];
      part[6] += xv[i] * r1[2]; part[7] += xv[i] * r1[3];
    }
#pragma unroll
    for (int off = 32; off > 0; off >>= 1) {
#pragma unroll
      for (int e = 0; e < NE; ++e) part[e] += __shfl_xor(part[e], off);
    }
    if (lane == 0) {
      int ia = 0;
#pragma unroll
      for (int e = 1; e < NE; ++e)
        if (part[e] > part[ia]) ia = e;
      int ib = (ia == 0) ? 1 : 0;
#pragma unroll
      for (int e = 0; e < NE; ++e)
        if (e != ia && e != ib && part[e] > part[ib]) ib = e;
      const float wa = 1.f / (1.f + __expf(part[ib] - part[ia]));
      tope[t * 2] = ia;
      tope[t * 2 + 1] = ib;
      topw[t * 2] = wa;
      topw[t * 2 + 1] = 1.f - wa;
    }
  } else {
    const int i = (bx - 512) * 256 + tid;  // 0..2047
    for (int j = i; j < PCAP; j += 2048) { pair_t[j] = 0; pair_w[j] = 0.f; }
    if (i < MAXMB) sched_e[i] = -1;
  }
}

// ---------------- k2: w1/w3 transposes (0..2047) + build (block 2048) ----------------
__global__ __launch_bounds__(256) void trans13_build_kernel(
    const float* __restrict__ w1, const float* __restrict__ w3,
    __bf16* __restrict__ w1t, __bf16* __restrict__ w3t,
    const int* __restrict__ tope, const float* __restrict__ topw,
    int* __restrict__ pair_t, float* __restrict__ pair_w,
    int* __restrict__ pairidx, int* __restrict__ sched_e) {
  const int bx = blockIdx.x;
  const int tid = threadIdx.x;
  if (bx < 2048) {
    __shared__ __bf16 tile[64][65];
    const float* src;
    __bf16* dst;
    int idx;
    if (bx < 1024) { src = w1; dst = w1t; idx = bx; }
    else           { src = w3; dst = w3t; idx = bx - 1024; }
    const int R = 512, C = 1024;
    const int ntx = C >> 6, nty = R >> 6;
    const int cx = idx % ntx;
    const int gry = idx / ntx;
    const int e = gry / nty;
    const int r0 = (gry % nty) * 64;
    const int c0 = cx * 64;
    src += (size_t)e * R * C;
    dst += (size_t)e * R * C;
#pragma unroll
    for (int q = 0; q < 4; ++q) {
      const int r = (tid >> 4) + q * 16;
      const int c = (tid & 15) * 4;
      const f32x4 v = *(const f32x4*)&src[(size_t)(r0 + r) * C + c0 + c];
      tile[r][c] = (__bf16)v[0];
      tile[r][c + 1] = (__bf16)v[1];
      tile[r][c + 2] = (__bf16)v[2];
      tile[r][c + 3] = (__bf16)v[3];
    }
    __syncthreads();
#pragma unroll
    for (int p = 0; p < 2; ++p) {
      const int cc = (tid >> 3) + p * 32;
      const int rr = (tid & 7) * 8;
      union { bf16x8 v; __bf16 s[8]; } u;
#pragma unroll
      for (int i = 0; i < 8; ++i) u.s[i] = tile[rr + i][cc];
      *(bf16x8*)&dst[(size_t)(c0 + cc) * R + r0 + rr] = u.v;
    }
  } else {
    __shared__ int cnt[NE], base[NE], ofs[NE];
    if (tid < NE) { cnt[tid] = 0; ofs[tid] = 0; }
    __syncthreads();
    for (int t = tid; t < T_TOK; t += 256) {
      atomicAdd(&cnt[tope[t * 2]], 1);
      atomicAdd(&cnt[tope[t * 2 + 1]], 1);
    }
    __syncthreads();
    if (tid == 0) {
      int mb = 0;
      for (int e = 0; e < NE; ++e) {
        base[e] = mb * 128;
        const int nmb = (cnt[e] + 127) >> 7;
        for (int i = 0; i < nmb; ++i) sched_e[mb + i] = e;
        mb += nmb;
      }
    }
    __syncthreads();
    for (int t = tid; t < T_TOK; t += 256) {
#pragma unroll
      for (int s = 0; s < 2; ++s) {
        const int e = tope[t * 2 + s];
        const int pos = base[e] + atomicAdd(&ofs[e], 1);
        pair_t[pos] = t;
        pair_w[pos] = topw[t * 2 + s];
        pairidx[t * 2 + s] = pos;
      }
    }
  }
}

// ---------------- k3: GEMM1 (blocks 0..639) + w2 transpose (640..1663) ----------------
__global__ __launch_bounds__(256) void gemm1_kernel(
    const __bf16* __restrict__ xb, const __bf16* __restrict__ w1t,
    const __bf16* __restrict__ w3t, const float* __restrict__ w2,
    __bf16* __restrict__ w2t, const int* __restrict__ pair_t,
    const float* __restrict__ pair_w, const int* __restrict__ sched_e,
    __bf16* __restrict__ hbuf) {
  __shared__ alignas(16) char smem[33280];
  const int tid = threadIdx.x;
  const int id = blockIdx.x;

  if (id >= 640) {
    __bf16(*tile)[65] = (__bf16(*)[65])smem;
    const int bx = id - 640;
    const int R = 1024, C = 512;
    const int ntx = C >> 6, nty = R >> 6;
    const int cx = bx % ntx;
    const int gry = bx / ntx;
    const int e = gry / nty;
    const int r0 = (gry % nty) * 64;
    const int c0 = cx * 64;
    const float* src = w2 + (size_t)e * R * C;
    __bf16* dst = w2t + (size_t)e * R * C;
#pragma unroll
    for (int q = 0; q < 4; ++q) {
      const int r = (tid >> 4) + q * 16;
      const int c = (tid & 15) * 4;
      const f32x4 v = *(const f32x4*)&src[(size_t)(r0 + r) * C + c0 + c];
      tile[r][c] = (__bf16)v[0];
      tile[r][c + 1] = (__bf16)v[1];
      tile[r][c + 2] = (__bf16)v[2];
      tile[r][c + 3] = (__bf16)v[3];
    }
    __syncthreads();
#pragma unroll
    for (int p = 0; p < 2; ++p) {
      const int cc = (tid >> 3) + p * 32;
      const int rr = (tid & 7) * 8;
      union { bf16x8 v; __bf16 s[8]; } u;
#pragma unroll
      for (int i = 0; i < 8; ++i) u.s[i] = tile[rr + i][cc];
      *(bf16x8*)&dst[(size_t)(c0 + cc) * R + r0 + rr] = u.v;
    }
    return;
  }

#define AS_BUF(b) (smem + (b)*8192)
#define B1S_BUF(b) (smem + 16384 + (b)*4096)
#define B3S_BUF(b) (smem + 24576 + (b)*4096)
  float* comb = (float*)(smem + 32768);
  const int mb = (id & 7) + ((id >> 7) << 3);
  const int f0 = ((id >> 3) & 15) * 64;
  const int e = sched_e[mb];
  if (e < 0) return;
  const int m0 = mb * 128;
  const int lane = tid & 63;
  const int wv = tid >> 6;
  const int wr = wv >> 1, wc = wv & 1;
  const int l15 = lane & 15, lhi = lane >> 4;
  const int ko = (lhi ^ ((l15 >> 1) & 3)) << 4;

  if (tid < 128) comb[tid] = pair_w[m0 + tid];

  size_t aoff[2];
  int lbA[2];
#pragma unroll
  for (int it = 0; it < 2; ++it) {
    const int chunk = it * 256 + tid;
    const int r = chunk >> 2;
    const int c8 = ((chunk & 3) ^ ((r >> 1) & 3)) * 8;
    aoff[it] = (size_t)pair_t[m0 + r] * DMODEL + c8;
    lbA[it] = (it * 256 + (tid & ~63)) * 16;
  }
  size_t boff;
  int lbB;
  {
    const int r = tid >> 2;
    const int c8 = ((tid & 3) ^ ((r >> 1) & 3)) * 8;
    boff = (size_t)(e * FFN + f0 + r) * DMODEL + c8;
    lbB = (tid & ~63) * 16;
  }

  const f32x4 fz = {0.f, 0.f, 0.f, 0.f};
  f32x4 acc1[4][2], acc3[4][2];
#pragma unroll
  for (int m = 0; m < 4; ++m)
#pragma unroll
    for (int n = 0; n < 2; ++n) { acc1[m][n] = fz; acc3[m][n] = fz; }

#define G1_STAGE(BUF, K0)                                                     \
  do {                                                                        \
    _Pragma("unroll") for (int it = 0; it < 2; ++it)                          \
        gload_lds16(xb + aoff[it] + (K0), AS_BUF(BUF) + lbA[it]);             \
    gload_lds16(w1t + boff + (K0), B1S_BUF(BUF) + lbB);                       \
    gload_lds16(w3t + boff + (K0), B3S_BUF(BUF) + lbB);                       \
  } while (0)

#define G1_COMPUTE(BUF)                                                       \
  do {                                                                        \
    __builtin_amdgcn_s_setprio(1);                                            \
    bf16x8 af[4], b1f[2], b3f[2];                                             \
    _Pragma("unroll") for (int m = 0; m < 4; ++m)                             \
        af[m] = *(const bf16x8*)(AS_BUF(BUF) +                                \
                                 (wr * 64 + m * 16 + l15) * 64 + ko);         \
    _Pragma("unroll") for (int n = 0; n < 2; ++n) {                           \
      const int ro = (wc * 32 + n * 16 + l15) * 64 + ko;                      \
      b1f[n] = *(const bf16x8*)(B1S_BUF(BUF) + ro);                           \
      b3f[n] = *(const bf16x8*)(B3S_BUF(BUF) + ro);                           \
    }                                                                         \
    _Pragma("unroll") for (int m = 0; m < 4; ++m)                             \
        _Pragma("unroll") for (int n = 0; n < 2; ++n) {                       \
      acc1[m][n] = __builtin_amdgcn_mfma_f32_16x16x32_bf16(af[m], b1f[n],     \
                                                           acc1[m][n], 0, 0, 0); \
      acc3[m][n] = __builtin_amdgcn_mfma_f32_16x16x32_bf16(af[m], b3f[n],     \
                                                           acc3[m][n], 0, 0, 0); \
    }                                                                         \
    __builtin_amdgcn_s_setprio(0);                                            \
  } while (0)

  G1_STAGE(0, 0);
#pragma unroll
  for (int t = 0; t < 15; ++t) {
    G1_STAGE((t + 1) & 1, (t + 1) * 32);
    PIPE_BAR_4();
    G1_COMPUTE(t & 1);
    POST_BAR();
  }
  PIPE_BAR_0();
  G1_COMPUTE(1);

  __syncthreads();
  {
    __bf16* eps = (__bf16*)smem;
    constexpr int EW = 72;
#pragma unroll
    for (int m = 0; m < 4; ++m)
#pragma unroll
      for (int n = 0; n < 2; ++n)
#pragma unroll
        for (int r = 0; r < 4; ++r) {
          const int row = wr * 64 + m * 16 + lhi * 4 + r;
          const int col = wc * 32 + n * 16 + l15;
          const float g = acc1[m][n][r];
          const float u = acc3[m][n][r];
          eps[row * EW + col] = (__bf16)((g / (1.f + __expf(-g))) * u * comb[row]);
        }
    __syncthreads();
#pragma unroll
    for (int p = 0; p < 4; ++p) {
      const int i = p * 256 + tid;
      const int row = i >> 3, c8 = (i & 7) * 8;
      *(bf16x8*)&hbuf[(size_t)(m0 + row) * FFN + f0 + c8] =
          *(const bf16x8*)&eps[row * EW + c8];
    }
  }
#undef G1_STAGE
#undef G1_COMPUTE
#undef AS_BUF
#undef B1S_BUF
#undef B3S_BUF
}

// ---------------- k4: GEMM2 sparse: 128x64, BK=32, split-K=4, counted-vmcnt ----------------
// grid 1280: gk = (id&7)+((id>>6)<<3) in [0,160); n0 = ((id>>3)&7)*64;
// mb = gk>>2, kz = gk&3, K-range = [kz*256, kz*256+256), 8 K-steps.
__global__ __launch_bounds__(256) void gemm2_kernel(
    const __bf16* __restrict__ hbuf, const __bf16* __restrict__ w2t,
    const int* __restrict__ sched_e, __bf16* __restrict__ outp) {
  __shared__ alignas(16) char smem[24576];
#define AS_BUF(b) (smem + (b)*8192)
#define BS_BUF(b) (smem + 16384 + (b)*4096)
  const int tid = threadIdx.x;
  const int id = blockIdx.x;
  const int gk = (id & 7) + ((id >> 6) << 3);
  const int n0 = ((id >> 3) & 7) * 64;
  const int mb = gk >> 2;
  const int kz = gk & 3;
  const int e = sched_e[mb];
  if (e < 0) return;
  const int m0 = mb * 128;
  const int fbase = kz * (FFN / 4);
  const int lane = tid & 63;
  const int wv = tid >> 6;
  const int wr = wv >> 1, wc = wv & 1;
  const int l15 = lane & 15, lhi = lane >> 4;
  const int ko = (lhi ^ ((l15 >> 1) & 3)) << 4;

  size_t aoff[2];
  int lbA[2];
#pragma unroll
  for (int it = 0; it < 2; ++it) {
    const int chunk = it * 256 + tid;
    const int r = chunk >> 2;
    const int c8 = ((chunk & 3) ^ ((r >> 1) & 3)) * 8;
    aoff[it] = (size_t)(m0 + r) * FFN + fbase + c8;
    lbA[it] = (it * 256 + (tid & ~63)) * 16;
  }
  size_t boff;
  int lbB;
  {
    const int r = tid >> 2;
    const int c8 = ((tid & 3) ^ ((r >> 1) & 3)) * 8;
    boff = ((size_t)e * DMODEL + n0 + r) * FFN + fbase + c8;
    lbB = (tid & ~63) * 16;
  }

  const f32x4 fz = {0.f, 0.f, 0.f, 0.f};
  f32x4 acc[4][2];
#pragma unroll
  for (int m = 0; m < 4; ++m) { acc[m][0] = fz; acc[m][1] = fz; }

#define G2_STAGE(BUF, K0)                                                     \
  do {                                                                        \
    _Pragma("unroll") for (int it = 0; it < 2; ++it)                          \
        gload_lds16(hbuf + aoff[it] + (K0), AS_BUF(BUF) + lbA[it]);           \
    gload_lds16(w2t + boff + (K0), BS_BUF(BUF) + lbB);                        \
  } while (0)

#define G2_COMPUTE(BUF)                                                       \
  do {                                                                        \
    __builtin_amdgcn_s_setprio(1);                                            \
    bf16x8 af[4], bfr[2];                                                     \
    _Pragma("unroll") for (int m = 0; m < 4; ++m)                             \
        af[m] = *(const bf16x8*)(AS_BUF(BUF) +                                \
                                 (wr * 64 + m * 16 + l15) * 64 + ko);         \
    _Pragma("unroll") for (int n = 0; n < 2; ++n)                             \
        bfr[n] = *(const bf16x8*)(BS_BUF(BUF) +                               \
                                  (wc * 32 + n * 16 + l15) * 64 + ko);        \
    _Pragma("unroll") for (int m = 0; m < 4; ++m)                             \
        _Pragma("unroll") for (int n = 0; n < 2; ++n)                         \
            acc[m][n] = __builtin_amdgcn_mfma_f32_16x16x32_bf16(              \
                af[m], bfr[n], acc[m][n], 0, 0, 0);                           \
    __builtin_amdgcn_s_setprio(0);                                            \
  } while (0)

  G2_STAGE(0, 0);
#pragma unroll
  for (int t = 0; t < 7; ++t) {
    G2_STAGE((t + 1) & 1, (t + 1) * 32);
    PIPE_BAR_3();
    G2_COMPUTE(t & 1);
    POST_BAR();
  }
  PIPE_BAR_0();
  G2_COMPUTE(1);

  __syncthreads();
  {
    __bf16* eps = (__bf16*)smem;
    constexpr int EW = 72;
#pragma unroll
    for (int m = 0; m < 4; ++m)
#pragma unroll
      for (int n = 0; n < 2; ++n)
#pragma unroll
        for (int r = 0; r < 4; ++r) {
          const int row = wr * 64 + m * 16 + lhi * 4 + r;
          const int col = wc * 32 + n * 16 + l15;
          eps[row * EW + col] = (__bf16)acc[m][n][r];
        }
    __syncthreads();
#pragma unroll
    for (int p = 0; p < 4; ++p) {
      const int i = p * 256 + tid;
      const int row = i >> 3, c8 = (i & 7) * 8;
      *(bf16x8*)&outp[((size_t)kz * PCAP + m0 + row) * DMODEL + n0 + c8] =
          *(const bf16x8*)&eps[row * EW + c8];
    }
  }
#undef G2_STAGE
#undef G2_COMPUTE
#undef AS_BUF
#undef BS_BUF
}

// ---------------- k5: gather: out[t] = sum of 2 pairs x 4 kz ----------------
__global__ __launch_bounds__(256) void gather_kernel(
    const __bf16* __restrict__ outp, const int* __restrict__ pairidx,
    float* __restrict__ out) {
  const int i = blockIdx.x * 256 + threadIdx.x;
  const int t = i >> 6;
  const int c = (i & 63) * 8;
  const int p0 = pairidx[t * 2];
  const int p1 = pairidx[t * 2 + 1];
  const size_t KZ = (size_t)PCAP * DMODEL;
  const size_t s0 = (size_t)p0 * DMODEL + c;
  const size_t s1 = (size_t)p1 * DMODEL + c;
  float acc[8];
#pragma unroll
  for (int j = 0; j < 8; ++j) acc[j] = 0.f;
#pragma unroll
  for (int kz = 0; kz < 4; ++kz) {
    const bf16x8 a = *(const bf16x8*)&outp[kz * KZ + s0];
    const bf16x8 b = *(const bf16x8*)&outp[kz * KZ + s1];
#pragma unroll
    for (int j = 0; j < 8; ++j) acc[j] += (float)a[j] + (float)b[j];
  }
  float* op = out + (size_t)t * DMODEL + c;
  f32x4 lo = {acc[0], acc[1], acc[2], acc[3]};
  f32x4 hi = {acc[4], acc[5], acc[6], acc[7]};
  *(f32x4*)op = lo;
  *(f32x4*)(op + 4) = hi;
}

extern "C" void kernel_launch(void* const* d_in, const int* in_sizes, int n_in,
                              void* d_out, int out_size, void* d_ws, size_t ws_size,
                              hipStream_t stream) {
  const float* x = (const float*)d_in[0];
  const float* rw = (const float*)d_in[1];
  const float* w1 = (const float*)d_in[2];
  const float* w2 = (const float*)d_in[3];
  const float* w3 = (const float*)d_in[4];
  float* out = (float*)d_out;
  char* ws = (char*)d_ws;

  int* tope = (int*)(ws + 0);                  //    16,384
  float* topw = (float*)(ws + 16384);          //    16,384
  int* pair_t = (int*)(ws + 32768);            //    20,480
  float* pair_w = (float*)(ws + 53248);        //    20,480
  int* pairidx = (int*)(ws + 73728);           //    16,384
  int* sched_e = (int*)(ws + 90112);           //     8,192 (padded)
  __bf16* xb = (__bf16*)(ws + 98304);          // 2,097,152
  __bf16* w1t = (__bf16*)(ws + 2195456);       // 8,388,608  [E][F][D]
  __bf16* w3t = (__bf16*)(ws + 10584064);      // 8,388,608  [E][F][D]
  __bf16* w2t = (__bf16*)(ws + 18972672);      // 8,388,608  [E][D][F]
  __bf16* hbuf = (__bf16*)(ws + 27361280);     // 10,485,760 [PCAP][F]
  __bf16* outp = (__bf16*)(ws + 37847040);     // 20,971,520 [4][PCAP][D] bf16

  hipLaunchKernelGGL(router_kernel, dim3(520), dim3(256), 0, stream,
                     x, rw, xb, tope, topw, pair_t, pair_w, sched_e);
  hipLaunchKernelGGL(trans13_build_kernel, dim3(2049), dim3(256), 0, stream,
                     w1, w3, w1t, w3t, tope, topw, pair_t, pair_w, pairidx, sched_e);
  hipLaunchKernelGGL(gemm1_kernel, dim3(640 + 1024), dim3(256), 0, stream,
                     xb, w1t, w3t, w2, w2t, pair_t, pair_w, sched_e, hbuf);
  hipLaunchKernelGGL(gemm2_kernel, dim3(1280), dim3(256), 0, stream,
                     hbuf, w2t, sched_e, outp);
  hipLaunchKernelGGL(gather_kernel, dim3(512), dim3(256), 0, stream,
                     outp, pairidx, out);
}

// Round 17
// 66.722 us; speedup vs baseline: 1.0037x; 1.0037x over previous
//
#include <hip/hip_runtime.h>
#include <hip/hip_bf16.h>

// MoE forward, top-2 sparse gather-GEMM.  FINAL (= Round 15, best measured 66.7us).
// T=2048, D=512, F=1024, E=8, top-2. fp32 in/out, bf16 MFMA internally.
//
// Structure (validated over 16 rounds; 172.8us naive-dense -> 66.7us):
//   k1 router: x->bf16 + top-2 softmax weights + pair/sched init (520 blocks)
//   k2 trans13+build: w1/w3 transpose+cvt tiles (0..2047) co-launched with the
//      1-block expert-list build (block 2048) -> build hides under BW stream
//   k3 gemm1 (0..639: 128x64-tile BK=32 counted-vmcnt MFMA, silu*up*w epilogue)
//      + w2 transpose tiles (640..1663) hiding under gemm1's latency-bound run
//   k4 gemm2: split-K=2, 128x64 tiles, BK=32, counted-vmcnt
//   k5 gather: deterministic 2-pair x 2-kz sum (bf16 partials, fp32 accum)
// Key measured levers: XOR-swizzled LDS (bank conflicts 9.4M->0), counted
// vmcnt pipeline (no vmcnt(0) drain in K-loop), BK=32 for occupancy
// (4-6 blocks/CU; occupancy > pipeline-depth on this chip), top-2 sparsity
// (4x compute cut), prep-traffic hidden under latency-bound GEMM slots.

typedef __attribute__((ext_vector_type(4))) float f32x4;
typedef __attribute__((ext_vector_type(8))) __bf16 bf16x8;

#define T_TOK 2048
#define DMODEL 512
#define FFN 1024
#define NE 8
#define MAXMB 40
#define PCAP (MAXMB * 128)

__device__ __forceinline__ void gload_lds16(const void* g, void* l) {
  __builtin_amdgcn_global_load_lds(
      (const __attribute__((address_space(1))) void*)g,
      (__attribute__((address_space(3))) void*)l, 16, 0, 0);
}

#define PIPE_BAR_4()                                        \
  asm volatile("s_waitcnt vmcnt(4)" ::: "memory");          \
  __builtin_amdgcn_s_barrier();                             \
  __builtin_amdgcn_sched_barrier(0)
#define PIPE_BAR_3()                                        \
  asm volatile("s_waitcnt vmcnt(3)" ::: "memory");          \
  __builtin_amdgcn_s_barrier();                             \
  __builtin_amdgcn_sched_barrier(0)
#define PIPE_BAR_0()                                        \
  asm volatile("s_waitcnt vmcnt(0)" ::: "memory");          \
  __builtin_amdgcn_s_barrier();                             \
  __builtin_amdgcn_sched_barrier(0)
#define POST_BAR()                                          \
  __builtin_amdgcn_s_barrier();                             \
  __builtin_amdgcn_sched_barrier(0)

// ---------------- k1: router (x->bf16 + top-2) + inits ----------------
__global__ __launch_bounds__(256) void router_kernel(
    const float* __restrict__ x, const float* __restrict__ rw,
    __bf16* __restrict__ xb, int* __restrict__ tope, float* __restrict__ topw,
    int* __restrict__ pair_t, float* __restrict__ pair_w,
    int* __restrict__ sched_e) {
  const int bx = blockIdx.x;
  const int tid = threadIdx.x;
  if (bx < 512) {
    const int t = bx * 4 + (tid >> 6);
    const int lane = tid & 63;
    const float* xr = x + (size_t)t * DMODEL + lane * 8;
    const f32x4 a = *(const f32x4*)xr;
    const f32x4 b = *(const f32x4*)(xr + 4);
    bf16x8 v;
    v[0] = (__bf16)a[0]; v[1] = (__bf16)a[1]; v[2] = (__bf16)a[2]; v[3] = (__bf16)a[3];
    v[4] = (__bf16)b[0]; v[5] = (__bf16)b[1]; v[6] = (__bf16)b[2]; v[7] = (__bf16)b[3];
    *(bf16x8*)&xb[(size_t)t * DMODEL + lane * 8] = v;

    float xv[8] = {a[0], a[1], a[2], a[3], b[0], b[1], b[2], b[3]};
    float part[NE];
#pragma unroll
    for (int e = 0; e < NE; ++e) part[e] = 0.f;
#pragma unroll
    for (int i = 0; i < 8; ++i) {
      const int d = lane * 8 + i;
      const f32x4 r0 = *(const f32x4*)&rw[(size_t)d * NE];
      const f32x4 r1 = *(const f32x4*)&rw[(size_t)d * NE + 4];
      part[0] += xv[i] * r0[0]; part[1] += xv[i] * r0[1];
      part[2] += xv[i] * r0[2]; part[3] += xv[i] * r0[3];
      part[4] += xv[i] * r1[0]; part[5] += xv[i] * r1[1];
      part[6] += xv[i] * r1[2]; part[7] += xv[i] * r1[3];
    }
#pragma unroll
    for (int off = 32; off > 0; off >>= 1) {
#pragma unroll
      for (int e = 0; e < NE; ++e) part[e] += __shfl_xor(part[e], off);
    }
    if (lane == 0) {
      int ia = 0;
#pragma unroll
      for (int e = 1; e < NE; ++e)
        if (part[e] > part[ia]) ia = e;
      int ib = (ia == 0) ? 1 : 0;
#pragma unroll
      for (int e = 0; e < NE; ++e)
        if (e != ia && e != ib && part[e] > part[ib]) ib = e;
      const float wa = 1.f / (1.f + __expf(part[ib] - part[ia]));
      tope[t * 2] = ia;
      tope[t * 2 + 1] = ib;
      topw[t * 2] = wa;
      topw[t * 2 + 1] = 1.f - wa;
    }
  } else {
    // ---- init pair lists (padding rows = token 0, weight 0) + schedule ----
    const int i = (bx - 512) * 256 + tid;  // 0..2047
    for (int j = i; j < PCAP; j += 2048) { pair_t[j] = 0; pair_w[j] = 0.f; }
    if (i < MAXMB) sched_e[i] = -1;
  }
}

// ---------------- k2: w1/w3 transposes (0..2047) + build (block 2048) ----------------
__global__ __launch_bounds__(256) void trans13_build_kernel(
    const float* __restrict__ w1, const float* __restrict__ w3,
    __bf16* __restrict__ w1t, __bf16* __restrict__ w3t,
    const int* __restrict__ tope, const float* __restrict__ topw,
    int* __restrict__ pair_t, float* __restrict__ pair_w,
    int* __restrict__ pairidx, int* __restrict__ sched_e) {
  const int bx = blockIdx.x;
  const int tid = threadIdx.x;
  if (bx < 2048) {
    __shared__ __bf16 tile[64][65];
    const float* src;
    __bf16* dst;
    int idx;
    if (bx < 1024) { src = w1; dst = w1t; idx = bx; }
    else           { src = w3; dst = w3t; idx = bx - 1024; }
    const int R = 512, C = 1024;
    const int ntx = C >> 6, nty = R >> 6;
    const int cx = idx % ntx;
    const int gry = idx / ntx;
    const int e = gry / nty;
    const int r0 = (gry % nty) * 64;
    const int c0 = cx * 64;
    src += (size_t)e * R * C;
    dst += (size_t)e * R * C;
#pragma unroll
    for (int q = 0; q < 4; ++q) {
      const int r = (tid >> 4) + q * 16;
      const int c = (tid & 15) * 4;
      const f32x4 v = *(const f32x4*)&src[(size_t)(r0 + r) * C + c0 + c];
      tile[r][c] = (__bf16)v[0];
      tile[r][c + 1] = (__bf16)v[1];
      tile[r][c + 2] = (__bf16)v[2];
      tile[r][c + 3] = (__bf16)v[3];
    }
    __syncthreads();
#pragma unroll
    for (int p = 0; p < 2; ++p) {
      const int cc = (tid >> 3) + p * 32;
      const int rr = (tid & 7) * 8;
      union { bf16x8 v; __bf16 s[8]; } u;
#pragma unroll
      for (int i = 0; i < 8; ++i) u.s[i] = tile[rr + i][cc];
      *(bf16x8*)&dst[(size_t)(c0 + cc) * R + r0 + rr] = u.v;
    }
  } else {
    // ---- build: count + schedule + scatter (simple-atomic) ----
    __shared__ int cnt[NE], base[NE], ofs[NE];
    if (tid < NE) { cnt[tid] = 0; ofs[tid] = 0; }
    __syncthreads();
    for (int t = tid; t < T_TOK; t += 256) {
      atomicAdd(&cnt[tope[t * 2]], 1);
      atomicAdd(&cnt[tope[t * 2 + 1]], 1);
    }
    __syncthreads();
    if (tid == 0) {
      int mb = 0;
      for (int e = 0; e < NE; ++e) {
        base[e] = mb * 128;
        const int nmb = (cnt[e] + 127) >> 7;
        for (int i = 0; i < nmb; ++i) sched_e[mb + i] = e;
        mb += nmb;
      }
    }
    __syncthreads();
    for (int t = tid; t < T_TOK; t += 256) {
#pragma unroll
      for (int s = 0; s < 2; ++s) {
        const int e = tope[t * 2 + s];
        const int pos = base[e] + atomicAdd(&ofs[e], 1);
        pair_t[pos] = t;
        pair_w[pos] = topw[t * 2 + s];
        pairidx[t * 2 + s] = pos;
      }
    }
  }
}

// ---------------- k3: GEMM1 (blocks 0..639) + w2 transpose (640..1663) ----------------
__global__ __launch_bounds__(256) void gemm1_kernel(
    const __bf16* __restrict__ xb, const __bf16* __restrict__ w1t,
    const __bf16* __restrict__ w3t, const float* __restrict__ w2,
    __bf16* __restrict__ w2t, const int* __restrict__ pair_t,
    const float* __restrict__ pair_w, const int* __restrict__ sched_e,
    __bf16* __restrict__ hbuf) {
  __shared__ alignas(16) char smem[33280];
  const int tid = threadIdx.x;
  const int id = blockIdx.x;

  if (id >= 640) {
    // ---- w2 transpose + cvt: w2[e][1024][512] f32 -> w2t[e][512][1024] bf16 ----
    __bf16(*tile)[65] = (__bf16(*)[65])smem;
    const int bx = id - 640;
    const int R = 1024, C = 512;
    const int ntx = C >> 6, nty = R >> 6;
    const int cx = bx % ntx;
    const int gry = bx / ntx;
    const int e = gry / nty;
    const int r0 = (gry % nty) * 64;
    const int c0 = cx * 64;
    const float* src = w2 + (size_t)e * R * C;
    __bf16* dst = w2t + (size_t)e * R * C;
#pragma unroll
    for (int q = 0; q < 4; ++q) {
      const int r = (tid >> 4) + q * 16;
      const int c = (tid & 15) * 4;
      const f32x4 v = *(const f32x4*)&src[(size_t)(r0 + r) * C + c0 + c];
      tile[r][c] = (__bf16)v[0];
      tile[r][c + 1] = (__bf16)v[1];
      tile[r][c + 2] = (__bf16)v[2];
      tile[r][c + 3] = (__bf16)v[3];
    }
    __syncthreads();
#pragma unroll
    for (int p = 0; p < 2; ++p) {
      const int cc = (tid >> 3) + p * 32;
      const int rr = (tid & 7) * 8;
      union { bf16x8 v; __bf16 s[8]; } u;
#pragma unroll
      for (int i = 0; i < 8; ++i) u.s[i] = tile[rr + i][cc];
      *(bf16x8*)&dst[(size_t)(c0 + cc) * R + r0 + rr] = u.v;
    }
    return;
  }

#define AS_BUF(b) (smem + (b)*8192)
#define B1S_BUF(b) (smem + 16384 + (b)*4096)
#define B3S_BUF(b) (smem + 24576 + (b)*4096)
  float* comb = (float*)(smem + 32768);
  const int mb = (id & 7) + ((id >> 7) << 3);
  const int f0 = ((id >> 3) & 15) * 64;
  const int e = sched_e[mb];
  if (e < 0) return;
  const int m0 = mb * 128;
  const int lane = tid & 63;
  const int wv = tid >> 6;
  const int wr = wv >> 1, wc = wv & 1;
  const int l15 = lane & 15, lhi = lane >> 4;
  const int ko = (lhi ^ ((l15 >> 1) & 3)) << 4;

  if (tid < 128) comb[tid] = pair_w[m0 + tid];

  size_t aoff[2];
  int lbA[2];
#pragma unroll
  for (int it = 0; it < 2; ++it) {
    const int chunk = it * 256 + tid;
    const int r = chunk >> 2;
    const int c8 = ((chunk & 3) ^ ((r >> 1) & 3)) * 8;
    aoff[it] = (size_t)pair_t[m0 + r] * DMODEL + c8;
    lbA[it] = (it * 256 + (tid & ~63)) * 16;
  }
  size_t boff;
  int lbB;
  {
    const int r = tid >> 2;
    const int c8 = ((tid & 3) ^ ((r >> 1) & 3)) * 8;
    boff = (size_t)(e * FFN + f0 + r) * DMODEL + c8;
    lbB = (tid & ~63) * 16;
  }

  const f32x4 fz = {0.f, 0.f, 0.f, 0.f};
  f32x4 acc1[4][2], acc3[4][2];
#pragma unroll
  for (int m = 0; m < 4; ++m)
#pragma unroll
    for (int n = 0; n < 2; ++n) { acc1[m][n] = fz; acc3[m][n] = fz; }

#define G1_STAGE(BUF, K0)                                                     \
  do {                                                                        \
    _Pragma("unroll") for (int it = 0; it < 2; ++it)                          \
        gload_lds16(xb + aoff[it] + (K0), AS_BUF(BUF) + lbA[it]);             \
    gload_lds16(w1t + boff + (K0), B1S_BUF(BUF) + lbB);                       \
    gload_lds16(w3t + boff + (K0), B3S_BUF(BUF) + lbB);                       \
  } while (0)

#define G1_COMPUTE(BUF)                                                       \
  do {                                                                        \
    __builtin_amdgcn_s_setprio(1);                                            \
    bf16x8 af[4], b1f[2], b3f[2];                                             \
    _Pragma("unroll") for (int m = 0; m < 4; ++m)                             \
        af[m] = *(const bf16x8*)(AS_BUF(BUF) +                                \
                                 (wr * 64 + m * 16 + l15) * 64 + ko);         \
    _Pragma("unroll") for (int n = 0; n < 2; ++n) {                           \
      const int ro = (wc * 32 + n * 16 + l15) * 64 + ko;                      \
      b1f[n] = *(const bf16x8*)(B1S_BUF(BUF) + ro);                           \
      b3f[n] = *(const bf16x8*)(B3S_BUF(BUF) + ro);                           \
    }                                                                         \
    _Pragma("unroll") for (int m = 0; m < 4; ++m)                             \
        _Pragma("unroll") for (int n = 0; n < 2; ++n) {                       \
      acc1[m][n] = __builtin_amdgcn_mfma_f32_16x16x32_bf16(af[m], b1f[n],     \
                                                           acc1[m][n], 0, 0, 0); \
      acc3[m][n] = __builtin_amdgcn_mfma_f32_16x16x32_bf16(af[m], b3f[n],     \
                                                           acc3[m][n], 0, 0, 0); \
    }                                                                         \
    __builtin_amdgcn_s_setprio(0);                                            \
  } while (0)

  G1_STAGE(0, 0);
#pragma unroll
  for (int t = 0; t < 15; ++t) {
    G1_STAGE((t + 1) & 1, (t + 1) * 32);
    PIPE_BAR_4();
    G1_COMPUTE(t & 1);
    POST_BAR();
  }
  PIPE_BAR_0();
  G1_COMPUTE(1);

  __syncthreads();
  {
    __bf16* eps = (__bf16*)smem;
    constexpr int EW = 72;
#pragma unroll
    for (int m = 0; m < 4; ++m)
#pragma unroll
      for (int n = 0; n < 2; ++n)
#pragma unroll
        for (int r = 0; r < 4; ++r) {
          const int row = wr * 64 + m * 16 + lhi * 4 + r;
          const int col = wc * 32 + n * 16 + l15;
          const float g = acc1[m][n][r];
          const float u = acc3[m][n][r];
          eps[row * EW + col] = (__bf16)((g / (1.f + __expf(-g))) * u * comb[row]);
        }
    __syncthreads();
#pragma unroll
    for (int p = 0; p < 4; ++p) {
      const int i = p * 256 + tid;
      const int row = i >> 3, c8 = (i & 7) * 8;
      *(bf16x8*)&hbuf[(size_t)(m0 + row) * FFN + f0 + c8] =
          *(const bf16x8*)&eps[row * EW + c8];
    }
  }
#undef G1_STAGE
#undef G1_COMPUTE
#undef AS_BUF
#undef B1S_BUF
#undef B3S_BUF
}

// ---------------- k4: GEMM2 sparse: 128x64, BK=32, split-K=2, counted-vmcnt ----------------
__global__ __launch_bounds__(256) void gemm2_kernel(
    const __bf16* __restrict__ hbuf, const __bf16* __restrict__ w2t,
    const int* __restrict__ sched_e, __bf16* __restrict__ outp) {
  __shared__ alignas(16) char smem[24576];
#define AS_BUF(b) (smem + (b)*8192)
#define BS_BUF(b) (smem + 16384 + (b)*4096)
  const int tid = threadIdx.x;
  const int id = blockIdx.x;
  const int gk = (id & 7) + ((id >> 6) << 3);
  const int n0 = ((id >> 3) & 7) * 64;
  const int mb = gk >> 1;
  const int kz = gk & 1;
  const int e = sched_e[mb];
  if (e < 0) return;
  const int m0 = mb * 128;
  const int fbase = kz * (FFN / 2);
  const int lane = tid & 63;
  const int wv = tid >> 6;
  const int wr = wv >> 1, wc = wv & 1;
  const int l15 = lane & 15, lhi = lane >> 4;
  const int ko = (lhi ^ ((l15 >> 1) & 3)) << 4;

  size_t aoff[2];
  int lbA[2];
#pragma unroll
  for (int it = 0; it < 2; ++it) {
    const int chunk = it * 256 + tid;
    const int r = chunk >> 2;
    const int c8 = ((chunk & 3) ^ ((r >> 1) & 3)) * 8;
    aoff[it] = (size_t)(m0 + r) * FFN + fbase + c8;
    lbA[it] = (it * 256 + (tid & ~63)) * 16;
  }
  size_t boff;
  int lbB;
  {
    const int r = tid >> 2;
    const int c8 = ((tid & 3) ^ ((r >> 1) & 3)) * 8;
    boff = ((size_t)e * DMODEL + n0 + r) * FFN + fbase + c8;
    lbB = (tid & ~63) * 16;
  }

  const f32x4 fz = {0.f, 0.f, 0.f, 0.f};
  f32x4 acc[4][2];
#pragma unroll
  for (int m = 0; m < 4; ++m) { acc[m][0] = fz; acc[m][1] = fz; }

#define G2_STAGE(BUF, K0)                                                     \
  do {                                                                        \
    _Pragma("unroll") for (int it = 0; it < 2; ++it)                          \
        gload_lds16(hbuf + aoff[it] + (K0), AS_BUF(BUF) + lbA[it]);           \
    gload_lds16(w2t + boff + (K0), BS_BUF(BUF) + lbB);                        \
  } while (0)

#define G2_COMPUTE(BUF)                                                       \
  do {                                                                        \
    __builtin_amdgcn_s_setprio(1);                                            \
    bf16x8 af[4], bfr[2];                                                     \
    _Pragma("unroll") for (int m = 0; m < 4; ++m)                             \
        af[m] = *(const bf16x8*)(AS_BUF(BUF) +                                \
                                 (wr * 64 + m * 16 + l15) * 64 + ko);         \
    _Pragma("unroll") for (int n = 0; n < 2; ++n)                             \
        bfr[n] = *(const bf16x8*)(BS_BUF(BUF) +                               \
                                  (wc * 32 + n * 16 + l15) * 64 + ko);        \
    _Pragma("unroll") for (int m = 0; m < 4; ++m)                             \
        _Pragma("unroll") for (int n = 0; n < 2; ++n)                         \
            acc[m][n] = __builtin_amdgcn_mfma_f32_16x16x32_bf16(              \
                af[m], bfr[n], acc[m][n], 0, 0, 0);                           \
    __builtin_amdgcn_s_setprio(0);                                            \
  } while (0)

  G2_STAGE(0, 0);
#pragma unroll
  for (int t = 0; t < 15; ++t) {
    G2_STAGE((t + 1) & 1, (t + 1) * 32);
    PIPE_BAR_3();
    G2_COMPUTE(t & 1);
    POST_BAR();
  }
  PIPE_BAR_0();
  G2_COMPUTE(1);

  __syncthreads();
  {
    __bf16* eps = (__bf16*)smem;
    constexpr int EW = 72;
#pragma unroll
    for (int m = 0; m < 4; ++m)
#pragma unroll
      for (int n = 0; n < 2; ++n)
#pragma unroll
        for (int r = 0; r < 4; ++r) {
          const int row = wr * 64 + m * 16 + lhi * 4 + r;
          const int col = wc * 32 + n * 16 + l15;
          eps[row * EW + col] = (__bf16)acc[m][n][r];
        }
    __syncthreads();
#pragma unroll
    for (int p = 0; p < 4; ++p) {
      const int i = p * 256 + tid;
      const int row = i >> 3, c8 = (i & 7) * 8;
      *(bf16x8*)&outp[((size_t)kz * PCAP + m0 + row) * DMODEL + n0 + c8] =
          *(const bf16x8*)&eps[row * EW + c8];
    }
  }
#undef G2_STAGE
#undef G2_COMPUTE
#undef AS_BUF
#undef BS_BUF
}

// ---------------- k5: gather: out[t] = sum of 2 pairs x 2 kz ----------------
__global__ __launch_bounds__(256) void gather_kernel(
    const __bf16* __restrict__ outp, const int* __restrict__ pairidx,
    float* __restrict__ out) {
  const int i = blockIdx.x * 256 + threadIdx.x;
  const int t = i >> 6;
  const int c = (i & 63) * 8;
  const int p0 = pairidx[t * 2];
  const int p1 = pairidx[t * 2 + 1];
  const size_t KZ = (size_t)PCAP * DMODEL;
  const bf16x8 a0 = *(const bf16x8*)&outp[(size_t)p0 * DMODEL + c];
  const bf16x8 a1 = *(const bf16x8*)&outp[(size_t)p1 * DMODEL + c];
  const bf16x8 b0 = *(const bf16x8*)&outp[KZ + (size_t)p0 * DMODEL + c];
  const bf16x8 b1 = *(const bf16x8*)&outp[KZ + (size_t)p1 * DMODEL + c];
  f32x4 lo, hi;
#pragma unroll
  for (int j = 0; j < 4; ++j)
    lo[j] = (float)a0[j] + (float)a1[j] + (float)b0[j] + (float)b1[j];
#pragma unroll
  for (int j = 0; j < 4; ++j)
    hi[j] = (float)a0[j + 4] + (float)a1[j + 4] + (float)b0[j + 4] + (float)b1[j + 4];
  float* op = out + (size_t)t * DMODEL + c;
  *(f32x4*)op = lo;
  *(f32x4*)(op + 4) = hi;
}

extern "C" void kernel_launch(void* const* d_in, const int* in_sizes, int n_in,
                              void* d_out, int out_size, void* d_ws, size_t ws_size,
                              hipStream_t stream) {
  const float* x = (const float*)d_in[0];
  const float* rw = (const float*)d_in[1];
  const float* w1 = (const float*)d_in[2];
  const float* w2 = (const float*)d_in[3];
  const float* w3 = (const float*)d_in[4];
  float* out = (float*)d_out;
  char* ws = (char*)d_ws;

  int* tope = (int*)(ws + 0);                  //    16,384
  float* topw = (float*)(ws + 16384);          //    16,384
  int* pair_t = (int*)(ws + 32768);            //    20,480
  float* pair_w = (float*)(ws + 53248);        //    20,480
  int* pairidx = (int*)(ws + 73728);           //    16,384
  int* sched_e = (int*)(ws + 90112);           //     8,192 (padded)
  __bf16* xb = (__bf16*)(ws + 98304);          // 2,097,152
  __bf16* w1t = (__bf16*)(ws + 2195456);       // 8,388,608  [E][F][D]
  __bf16* w3t = (__bf16*)(ws + 10584064);      // 8,388,608  [E][F][D]
  __bf16* w2t = (__bf16*)(ws + 18972672);      // 8,388,608  [E][D][F]
  __bf16* hbuf = (__bf16*)(ws + 27361280);     // 10,485,760 [PCAP][F]
  __bf16* outp = (__bf16*)(ws + 37847040);     // 10,485,760 [2][PCAP][D] bf16

  hipLaunchKernelGGL(router_kernel, dim3(520), dim3(256), 0, stream,
                     x, rw, xb, tope, topw, pair_t, pair_w, sched_e);
  hipLaunchKernelGGL(trans13_build_kernel, dim3(2049), dim3(256), 0, stream,
                     w1, w3, w1t, w3t, tope, topw, pair_t, pair_w, pairidx, sched_e);
  hipLaunchKernelGGL(gemm1_kernel, dim3(640 + 1024), dim3(256), 0, stream,
                     xb, w1t, w3t, w2, w2t, pair_t, pair_w, sched_e, hbuf);
  hipLaunchKernelGGL(gemm2_kernel, dim3(640), dim3(256), 0, stream,
                     hbuf, w2t, sched_e, outp);
  hipLaunchKernelGGL(gather_kernel, dim3(512), dim3(256), 0, stream,
                     outp, pairidx, out);
}